// Round 9
// baseline (770.723 us; speedup 1.0000x reference)
//
#include <hip/hip_runtime.h>
#include <cstdint>
#include <cstddef>

// GAT 2-layer (N=8192, D=256), flash softmax with rank-1 scores, bf16 MFMA PV.
// Identities:
//   m_i = leaky(s_i + max_{adj} d_j)        (leaky monotone)
//   exp(leaky(x)) = max(e^x, e^{a x})
//   p_ij = adj ? max(Ep_i*F_j, Gp_i*H_j) : 0,  F=e^d, H=e^{a d} (FH interleaved),
//   Ep = rl*e^{s-m}, Gp = rl*e^{a s-m}.
// pv v5: block = 128 rows x 128 cols x K/4. K-loop batched: gen 4 chunks (K=128)
// of P into 32 KB LDS per phase, then 64 MFMAs with NO internal barrier
// (2 barriers per batch instead of 8). B-frags register-prefetched one chunk
// ahead (flight spans the gen phase). 3 blocks/CU.
// R9 fix: gemm Bs staging indexed for 64-col tile (br=fi>>4, bc4=fi&15); R8 used
// the 32-col mapping -> LDS overflow + wrong Wh.
// ws (64 MB): Wh @0 (8) | bits @8 (8) | bitsT @16 (8) | small @24 | Bpack @25 (4)
//             | pout @32 (4 x 8 MB k-split partials)

#define ALPHA 0.2f
#define NN 8192
#define DD 256

typedef __attribute__((ext_vector_type(8))) short short8;
typedef __attribute__((ext_vector_type(4))) float f32x4;

__device__ __forceinline__ unsigned bf16rne(float x) {
    union { float f; unsigned u; } c; c.f = x;
    return (c.u + 0x7fffu + ((c.u >> 16) & 1u)) >> 16;
}

#if __has_builtin(__builtin_amdgcn_cvt_pk_bf16_f32)
__device__ __forceinline__ unsigned pk_bf16(float a, float b) {
    return __builtin_bit_cast(unsigned, __builtin_amdgcn_cvt_pk_bf16_f32(a, b));
}
#else
__device__ __forceinline__ unsigned pk_bf16(float a, float b) {
    return bf16rne(a) | (bf16rne(b) << 16);
}
#endif

// ---------------- packbits: adj int32 [8192][8192] -> bits [8192][128] u64 ----------------
__global__ __launch_bounds__(256) void packbits(const int* __restrict__ adj,
                                                uint64_t* __restrict__ bits) {
    const int wid = blockIdx.x * 4 + (threadIdx.x >> 6);
    const int lane = threadIdx.x & 63;
    const int* rowp = adj + (size_t)wid * NN;
    uint64_t* dst = bits + (size_t)wid * 128;
    for (int it = 0; it < 32; it++) {
        const int* p = rowp + it * 256;
        int a0 = p[lane];
        int a1 = p[64 + lane];
        int a2 = p[128 + lane];
        int a3 = p[192 + lane];
        uint64_t m0 = __ballot(a0 != 0);
        uint64_t m1 = __ballot(a1 != 0);
        uint64_t m2 = __ballot(a2 != 0);
        uint64_t m3 = __ballot(a3 != 0);
        if (lane == 0) {
            dst[it * 4 + 0] = m0; dst[it * 4 + 1] = m1;
            dst[it * 4 + 2] = m2; dst[it * 4 + 3] = m3;
        }
    }
}

// ---------------- bits [i][w] -> bitsT [w][i] (64x64 dword tiles) ----------------
__global__ __launch_bounds__(256) void transp_bits(const uint32_t* __restrict__ bits32,
                                                   uint32_t* __restrict__ bitsT) {
    __shared__ uint32_t tile[64][65];
    const int t = threadIdx.x;
    const int i0 = (int)(blockIdx.x >> 2) * 64;
    const int w0 = (int)(blockIdx.x & 3) * 64;
#pragma unroll
    for (int p = 0; p < 4; p++) {
        int r = (t >> 4) + 16 * p;
        int c4 = (t & 15) * 4;
        uint4 v = *(const uint4*)(bits32 + (size_t)(i0 + r) * 256 + w0 + c4);
        tile[r][c4 + 0] = v.x; tile[r][c4 + 1] = v.y;
        tile[r][c4 + 2] = v.z; tile[r][c4 + 3] = v.w;
    }
    __syncthreads();
#pragma unroll
    for (int p = 0; p < 4; p++) {
        int wr = (t >> 4) + 16 * p;
        int i4 = (t & 15) * 4;
        uint4 o = {tile[i4][wr], tile[i4 + 1][wr], tile[i4 + 2][wr], tile[i4 + 3][wr]};
        *(uint4*)(bitsT + (size_t)(w0 + wr) * NN + i0 + i4) = o;
    }
}

// ---------------- GEMM: Wh[8192 x 256] = A @ B[256 x 256], fp32; packs Bpack ----------------
// 1024 blocks (4/CU): 256 row-tiles (32) x 4 col-quarters (64 cols).
__global__ __launch_bounds__(256) void gemm_k256(const float* __restrict__ A,
                                                 const float* __restrict__ B,
                                                 float* __restrict__ C,
                                                 unsigned short* __restrict__ Bpack) {
    __shared__ __align__(16) float At[32][36];
    __shared__ __align__(16) float2 Bs[32][32];
    const int t = threadIdx.x;
    const int m0 = (int)(blockIdx.x >> 2) * 32;
    const int cq = blockIdx.x & 3;
    const int r0 = (t >> 5) * 4;
    const int cl = t & 31;                        // float2 col idx within 64
    float acc[4][2];
#pragma unroll
    for (int i = 0; i < 4; i++) { acc[i][0] = 0.f; acc[i][1] = 0.f; }

    for (int k0 = 0; k0 < DD; k0 += 32) {
        {
            int row = t >> 3, kq = t & 7;
            float4 v = *(const float4*)(A + (size_t)(m0 + row) * DD + k0 + kq * 4);
            At[kq * 4 + 0][row] = v.x; At[kq * 4 + 1][row] = v.y;
            At[kq * 4 + 2][row] = v.z; At[kq * 4 + 3][row] = v.w;
        }
#pragma unroll
        for (int l2 = 0; l2 < 2; l2++) {
            int fi = l2 * 256 + t;
            int br = fi >> 4, bc4 = fi & 15;      // 32 k-rows x 16 float4 (64 cols)
            float4 v = *(const float4*)(B + (size_t)(k0 + br) * DD + cq * 64 + bc4 * 4);
            Bs[br][bc4 * 2] = {v.x, v.y};
            Bs[br][bc4 * 2 + 1] = {v.z, v.w};
        }
        __syncthreads();
#pragma unroll
        for (int k = 0; k < 32; k++) {
            float4 a0 = *(const float4*)&At[k][r0];
            float2 b = Bs[k][cl];
            float av[4] = {a0.x, a0.y, a0.z, a0.w};
#pragma unroll
            for (int i = 0; i < 4; i++) {
                acc[i][0] += av[i] * b.x;
                acc[i][1] += av[i] * b.y;
            }
        }
        __syncthreads();
    }
#pragma unroll
    for (int i = 0; i < 4; i++) {
        float2 v = {acc[i][0], acc[i][1]};
        *(float2*)(C + (size_t)(m0 + r0 + i) * DD + cq * 64 + cl * 2) = v;
    }
    const int jt = m0 >> 5;
    const int lq = ((r0 >> 3) & 3) * 16;
    const int i8 = r0 & 4;
#pragma unroll
    for (int cc = 0; cc < 2; cc++) {
        int c = cq * 64 + cl * 2 + cc;
        int ct = c >> 4;
        int lane = lq + (c & 15);
        uint2 pk;
        pk.x = pk_bf16(acc[0][cc], acc[1][cc]);
        pk.y = pk_bf16(acc[2][cc], acc[3][cc]);
        *(uint2*)(Bpack + ((size_t)(jt * 16 + ct) * 64 + lane) * 8 + i8) = pk;
    }
}

// ------- s,d row dots; FH[2i]=exp(d), FH[2i+1]=exp(a*d) (1 wave/row) -------
__global__ __launch_bounds__(256) void rowdots(const float* __restrict__ Wh,
                                               const float* __restrict__ a_src,
                                               const float* __restrict__ a_dst,
                                               float* __restrict__ s,
                                               float* __restrict__ dd,
                                               float* __restrict__ FH) {
    int wave = threadIdx.x >> 6;
    int lane = threadIdx.x & 63;
    int row = blockIdx.x * 4 + wave;
    float4 w = *(const float4*)(Wh + (size_t)row * DD + lane * 4);
    float4 as = *(const float4*)(a_src + lane * 4);
    float4 ad = *(const float4*)(a_dst + lane * 4);
    float ss = w.x * as.x + w.y * as.y + w.z * as.z + w.w * as.w;
    float sd = w.x * ad.x + w.y * ad.y + w.z * ad.z + w.w * ad.w;
#pragma unroll
    for (int off = 32; off; off >>= 1) {
        ss += __shfl_down(ss, off);
        sd += __shfl_down(sd, off);
    }
    if (lane == 0) {
        s[row] = ss; dd[row] = sd;
        FH[2 * row] = __expf(sd);
        FH[2 * row + 1] = __expf(ALPHA * sd);
    }
}

// ------ rowstats v3: 8 rows/block, lane-contiguous loads, masks via LDS ------
__global__ __launch_bounds__(256) void rowstats(const uint32_t* __restrict__ bits32,
                                                const float* __restrict__ s,
                                                const float* __restrict__ dd,
                                                const float* __restrict__ FH,
                                                float* __restrict__ Ep,
                                                float* __restrict__ Gp) {
    __shared__ uint32_t smk[2048];          // 8 rows x 256 words
    __shared__ float red[4][8];
    __shared__ float sEm[8], sEa[8];
    const int i0 = blockIdx.x * 8;
    const int t = threadIdx.x;
    const int wave = t >> 6, lane = t & 63;
    {
        const uint4* src = (const uint4*)(bits32 + (size_t)i0 * 256);
        uint4* d = (uint4*)smk;
        d[t] = src[t];
        d[t + 256] = src[t + 256];
    }
    __syncthreads();

    float mx[8];
#pragma unroll
    for (int r = 0; r < 8; r++) mx[r] = -3.0e38f;
#pragma unroll
    for (int q = 0; q < 8; q++) {
        float4 v = *(const float4*)(dd + 4 * (t + 256 * q));
        const int wq = 32 * q + (t >> 3);
        const int sh = (t & 7) * 4;
#pragma unroll
        for (int r = 0; r < 8; r++) {
            uint32_t b = smk[r * 256 + wq] >> sh;
            mx[r] = fmaxf(mx[r], (b & 1u) ? v.x : -3.0e38f);
            mx[r] = fmaxf(mx[r], (b & 2u) ? v.y : -3.0e38f);
            mx[r] = fmaxf(mx[r], (b & 4u) ? v.z : -3.0e38f);
            mx[r] = fmaxf(mx[r], (b & 8u) ? v.w : -3.0e38f);
        }
    }
#pragma unroll
    for (int r = 0; r < 8; r++) {
#pragma unroll
        for (int off = 32; off; off >>= 1) mx[r] = fmaxf(mx[r], __shfl_down(mx[r], off));
    }
    if (lane == 0) {
#pragma unroll
        for (int r = 0; r < 8; r++) red[wave][r] = mx[r];
    }
    __syncthreads();
    if (t < 8) {
        float dmax = fmaxf(fmaxf(red[0][t], red[1][t]), fmaxf(red[2][t], red[3][t]));
        float si = s[i0 + t];
        float e = si + dmax;
        float m = e >= 0.f ? e : ALPHA * e;
        sEm[t] = __expf(si - m);
        sEa[t] = __expf(ALPHA * si - m);
    }
    __syncthreads();
    float em[8], ea[8], sm[8];
#pragma unroll
    for (int r = 0; r < 8; r++) { em[r] = sEm[r]; ea[r] = sEa[r]; sm[r] = 0.f; }

#pragma unroll
    for (int q = 0; q < 16; q++) {
        float4 v = *(const float4*)(FH + 4 * (t + 256 * q));
        const int wq = 16 * q + (t >> 4);
        const int sh = (t & 15) * 2;
#pragma unroll
        for (int r = 0; r < 8; r++) {
            uint32_t b = smk[r * 256 + wq] >> sh;
            float c0 = fmaxf(em[r] * v.x, ea[r] * v.y);
            float c1 = fmaxf(em[r] * v.z, ea[r] * v.w);
            sm[r] += (b & 1u) ? c0 : 0.f;
            sm[r] += (b & 2u) ? c1 : 0.f;
        }
    }
#pragma unroll
    for (int r = 0; r < 8; r++) {
#pragma unroll
        for (int off = 32; off; off >>= 1) sm[r] += __shfl_down(sm[r], off);
    }
    __syncthreads();
    if (lane == 0) {
#pragma unroll
        for (int r = 0; r < 8; r++) red[wave][r] = sm[r];
    }
    __syncthreads();
    if (t < 8) {
        float rl = 1.0f / (red[0][t] + red[1][t] + red[2][t] + red[3][t]);
        Ep[i0 + t] = rl * sEm[t];
        Gp[i0 + t] = rl * sEa[t];
    }
}

// ---------------- PV via MFMA: pout[ks] = P @ Wh (K-quarter partial) ----------------
// 512 blocks x 256 thr: bx -> ks = bx&3, ch = (bx>>2)&1, ib = bx>>3.
// Block: 128 rows x 128 cols x 2048 K (64 chunks of 32, processed in 16 batches
// of 4). Per batch: gen 4 chunks of P into LDS, barrier, 64 MFMAs (no internal
// barrier, B register-prefetched one chunk ahead), barrier.
__global__ __launch_bounds__(256, 3) void pv_mfma(const unsigned short* __restrict__ Bpack,
                                                  const uint32_t* __restrict__ bitsT,
                                                  const float* __restrict__ FH,
                                                  const float* __restrict__ Ep,
                                                  const float* __restrict__ Gp,
                                                  float* __restrict__ pout) {
    __shared__ __align__(16) unsigned short fragA[4][4096];   // 4 chunks x (128r x 32k), 32 KB
    const int t = threadIdx.x;
    const int w = t >> 6, l = t & 63;
    const int bx = blockIdx.x;
    const int ks = bx & 3;
    const int ch = (bx >> 2) & 1;
    const int i0 = (bx >> 3) * 128;
    const int kbase = ks * 64;                    // 64 chunks per quarter
    const int ct0 = ch * 8;
    const int rg = w >> 1, cg = w & 1;

    // ---- P-gen mapping: thread t -> rows (t&31)+32e (e=0..3), k-quad kq = t>>5 ----
    const int rlane = t & 31;
    const int kq = t >> 5;
    float Epv[4], Gpv[4];
#pragma unroll
    for (int e = 0; e < 4; e++) {
        Epv[e] = Ep[i0 + rlane + 32 * e];
        Gpv[e] = Gp[i0 + rlane + 32 * e];
    }
    const int lanebase = (kq >> 1) * 16 + (rlane & 15);
    const int rbbase = rlane >> 4;
    const int khi = kq & 1;

    auto gen = [&](int cc, int ci) {
        const int jj = cc * 32 + kq * 4;
        float4 fh0 = *(const float4*)(FH + 2 * (size_t)jj);
        float4 fh1 = *(const float4*)(FH + 2 * (size_t)jj + 4);
        const uint32_t* bt = bitsT + (size_t)cc * NN + i0 + rlane;
        uint2* dst = (uint2*)&fragA[ci][0];
#pragma unroll
        for (int e = 0; e < 4; e++) {
            uint32_t b = bt[32 * e] >> (kq * 4);
            float p0 = (b & 1u) ? fmaxf(Epv[e] * fh0.x, Gpv[e] * fh0.y) : 0.f;
            float p1 = (b & 2u) ? fmaxf(Epv[e] * fh0.z, Gpv[e] * fh0.w) : 0.f;
            float p2 = (b & 4u) ? fmaxf(Epv[e] * fh1.x, Gpv[e] * fh1.y) : 0.f;
            float p3 = (b & 8u) ? fmaxf(Epv[e] * fh1.z, Gpv[e] * fh1.w) : 0.f;
            uint2 pk;
            pk.x = pk_bf16(p0, p1);
            pk.y = pk_bf16(p2, p3);
            dst[((rbbase + 2 * e) * 64 + lanebase) * 2 + khi] = pk;
        }
    };

    const unsigned short* bbase = Bpack + ((size_t)(ct0 + cg * 4) * 64 + l) * 8;

    f32x4 acc[4][4];
#pragma unroll
    for (int i = 0; i < 4; i++)
#pragma unroll
        for (int q = 0; q < 4; q++) acc[i][q] = (f32x4){0.f, 0.f, 0.f, 0.f};

    // prologue: B for first chunk
    short8 Bc[4];
    {
        const unsigned short* bp = bbase + (size_t)kbase * 8192;
#pragma unroll
        for (int q = 0; q < 4; q++) Bc[q] = *(const short8*)(bp + q * 512);
    }

    for (int b = 0; b < 16; b++) {
        // ---- gen phase: 4 chunks of P into LDS ----
#pragma unroll
        for (int ci = 0; ci < 4; ci++) gen(kbase + 4 * b + ci, ci);
        __syncthreads();
        // ---- consume phase: 4 chunks, no internal barrier ----
#pragma unroll
        for (int ci = 0; ci < 4; ci++) {
            const int cn = kbase + ((4 * b + ci + 1) & 63);
            const unsigned short* bp = bbase + (size_t)cn * 8192;
            short8 Bn[4];
#pragma unroll
            for (int q = 0; q < 4; q++) Bn[q] = *(const short8*)(bp + q * 512);
            short8 a[4];
#pragma unroll
            for (int ri = 0; ri < 4; ri++)
                a[ri] = *(const short8*)&fragA[ci][((rg * 4 + ri) * 64 + l) * 8];
#pragma unroll
            for (int ri = 0; ri < 4; ri++)
#pragma unroll
                for (int qi = 0; qi < 4; qi++)
                    acc[ri][qi] = __builtin_amdgcn_mfma_f32_16x16x32_bf16(a[ri], Bc[qi],
                                                                          acc[ri][qi], 0, 0, 0);
#pragma unroll
            for (int q = 0; q < 4; q++) Bc[q] = Bn[q];
        }
        __syncthreads();
    }

    float* outp = pout + (size_t)ks * NN * DD;
    // C layout: col = l&15, row = (l>>4)*4 + r
#pragma unroll
    for (int ri = 0; ri < 4; ri++) {
        const int orow = i0 + rg * 64 + ri * 16 + (l >> 4) * 4;
#pragma unroll
        for (int qi = 0; qi < 4; qi++) {
            const int ocol = (ct0 + cg * 4 + qi) * 16 + (l & 15);
#pragma unroll
            for (int r = 0; r < 4; r++)
                outp[(size_t)(orow + r) * DD + ocol] = acc[ri][qi][r];
        }
    }
}

// -------- out = relu(p0+p1+p2+p3) --------
__global__ __launch_bounds__(256) void combine4(const float* __restrict__ p,
                                                float* __restrict__ out) {
    const size_t S = (size_t)NN * DD / 4;   // float4 stride between partials
    size_t idx = (size_t)blockIdx.x * 256 + threadIdx.x;
    float4 a = ((const float4*)p)[idx];
    float4 b = ((const float4*)p)[idx + S];
    float4 c = ((const float4*)p)[idx + 2 * S];
    float4 d = ((const float4*)p)[idx + 3 * S];
    float4 o;
    o.x = fmaxf(a.x + b.x + c.x + d.x, 0.f);
    o.y = fmaxf(a.y + b.y + c.y + d.y, 0.f);
    o.z = fmaxf(a.z + b.z + c.z + d.z, 0.f);
    o.w = fmaxf(a.w + b.w + c.w + d.w, 0.f);
    ((float4*)out)[idx] = o;
}

extern "C" void kernel_launch(void* const* d_in, const int* in_sizes, int n_in,
                              void* d_out, int out_size, void* d_ws, size_t ws_size,
                              hipStream_t stream) {
    const float* x   = (const float*)d_in[0];
    const int* adj   = (const int*)d_in[1];
    const float* W1  = (const float*)d_in[2];
    const float* a1s = (const float*)d_in[3];
    const float* a1d = (const float*)d_in[4];
    const float* W2  = (const float*)d_in[5];
    const float* a2s = (const float*)d_in[6];
    const float* a2d = (const float*)d_in[7];
    float* out = (float*)d_out;

    char* ws = (char*)d_ws;
    const size_t MB = 1024ull * 1024ull;
    float*          Wh    = (float*)(ws);                    // 8 MB
    uint64_t*       bits  = (uint64_t*)(ws + 8 * MB);        // 8 MB
    uint32_t*       bits32= (uint32_t*)bits;
    uint32_t*       bitsT = (uint32_t*)(ws + 16 * MB);       // 8 MB
    float*          sArr  = (float*)(ws + 24 * MB);
    float*          ddA   = sArr + NN;
    float*          EpA   = sArr + 2 * NN;
    float*          GpA   = sArr + 3 * NN;
    float*          FHA   = sArr + 4 * NN;                   // 2*NN floats
    unsigned short* Bpack = (unsigned short*)(ws + 25 * MB); // 4 MB
    float*          pout  = (float*)(ws + 32 * MB);          // 32 MB (4 partials)

    packbits<<<dim3(2048), dim3(256), 0, stream>>>(adj, bits);
    transp_bits<<<dim3(512), dim3(256), 0, stream>>>(bits32, bitsT);

    // ---------------- Layer 1 ----------------
    gemm_k256<<<dim3(1024), dim3(256), 0, stream>>>(x, W1, Wh, Bpack);
    rowdots<<<dim3(2048), dim3(256), 0, stream>>>(Wh, a1s, a1d, sArr, ddA, FHA);
    rowstats<<<dim3(1024), dim3(256), 0, stream>>>(bits32, sArr, ddA, FHA, EpA, GpA);
    pv_mfma<<<dim3(512), dim3(256), 0, stream>>>(Bpack, bitsT, FHA, EpA, GpA, pout);
    combine4<<<dim3(2048), dim3(256), 0, stream>>>(pout, out);

    // ---------------- Layer 2 ----------------
    gemm_k256<<<dim3(1024), dim3(256), 0, stream>>>(out, W2, Wh, Bpack);
    rowdots<<<dim3(2048), dim3(256), 0, stream>>>(Wh, a2s, a2d, sArr, ddA, FHA);
    rowstats<<<dim3(1024), dim3(256), 0, stream>>>(bits32, sArr, ddA, FHA, EpA, GpA);
    pv_mfma<<<dim3(512), dim3(256), 0, stream>>>(Bpack, bitsT, FHA, EpA, GpA, pout);
    combine4<<<dim3(2048), dim3(256), 0, stream>>>(pout, out);
}